// Round 1
// baseline (781.271 us; speedup 1.0000x reference)
//
#include <hip/hip_runtime.h>

#define NQ 8192
#define CD 128
#define NB 2
#define KNN 20
#define QB 64    // queries per block (knn kernel)
#define TB 128   // candidates per tile

// ---------------- transpose (B,C,N) -> (B,N,C) ----------------
__global__ __launch_bounds__(256) void k_transpose(const float* __restrict__ x,
                                                   float* __restrict__ vf) {
  __shared__ float tile[32][33];
  int bid = blockIdx.x;
  int ctile = bid & 3;            // CD/32 = 4
  int ntile = (bid >> 2) & 255;   // NQ/32 = 256
  int b = bid >> 10;
  int c0 = ctile << 5, n0 = ntile << 5;
  int tx = threadIdx.x & 31, ty = threadIdx.x >> 5;  // ty 0..7
  const float* xb = x + (size_t)b * CD * NQ;
  float* vb = vf + (size_t)b * NQ * CD;
#pragma unroll
  for (int i = 0; i < 4; ++i) {
    int c = ty + (i << 3);
    tile[c][tx] = xb[(size_t)(c0 + c) * NQ + n0 + tx];
  }
  __syncthreads();
#pragma unroll
  for (int i = 0; i < 4; ++i) {
    int n = ty + (i << 3);
    vb[(size_t)(n0 + n) * CD + c0 + tx] = tile[tx][n];
  }
}

// ---------------- per-row sum of squares ----------------
__global__ __launch_bounds__(256) void k_xx(const float* __restrict__ vf,
                                            float* __restrict__ xx) {
  int g = blockIdx.x * 256 + threadIdx.x;  // row id over NB*NQ
  const float4* row = (const float4*)(vf + (size_t)g * CD);
  float s = 0.f;
#pragma unroll
  for (int i = 0; i < CD / 4; ++i) {
    float4 v = row[i];
    s += v.x * v.x + v.y * v.y + v.z * v.z + v.w * v.w;
  }
  xx[g] = s;
}

// ---------------- fused distance GEMM + exact top-20 ----------------
// grid: 256 blocks (128 q-blocks per batch), 512 threads (8 waves)
// LDS: qf 64x132, cf 128x132, sd 64x132  (~136 KB -> 1 block/CU)
__global__ __launch_bounds__(512, 2) void k_knn(const float* __restrict__ vf,
                                                const float* __restrict__ xx,
                                                int* __restrict__ idxout) {
  __shared__ float qf[QB][132];
  __shared__ float cf[TB][132];
  __shared__ float sd[QB][132];
  __shared__ float xq[QB];
  __shared__ float xc[TB];

  int t = threadIdx.x;
  int blk = blockIdx.x;
  int b = blk >> 7;
  int q0 = (blk & 127) * QB;
  const float* vb = vf + (size_t)b * NQ * CD;
  const float* xb = xx + (size_t)b * NQ;

  // stage query tile (full K)
#pragma unroll
  for (int i = 0; i < 4; ++i) {
    int e = t + i * 512;               // 0..2047 (64 rows x 32 f4)
    int r = e >> 5, c4 = (e & 31) << 2;
    *(float4*)&qf[r][c4] = *(const float4*)&vb[(size_t)(q0 + r) * CD + c4];
  }
  if (t < QB) xq[t] = xb[q0 + t];

  int lane = t & 63, w = t >> 6;       // wave id 0..7
  int ct = t & 31, qt = t >> 5;        // compute mapping: 16 qt x 32 ct

  // wave-distributed top-20 state: 8 queries per wave; list element of rank
  // `lane` lives in lane (lanes 0..19 meaningful), sorted ascending.
  float ed[8]; int ei[8]; float tau[8]; int qg[8];
#pragma unroll
  for (int u = 0; u < 8; ++u) {
    ed[u] = 3.0e38f; ei[u] = 0; tau[u] = 3.0e38f; qg[u] = q0 + 8 * w + u;
  }

  // wave-cooperative insert into sorted distributed list
  auto insert1 = [&](float& edu, int& eiu, float& tauu, float d, int ci) {
    float cur = edu; int curi = eiu;
    float sh = __shfl_up(cur, 1);
    int shi = __shfl_up(curi, 1);
    bool cprev = (lane > 0) && (d < sh);
    bool ccur = d < cur;
    edu = ccur ? (cprev ? sh : d) : cur;
    eiu = ccur ? (cprev ? shi : ci) : curi;
    tauu = __shfl(edu, 19);
  };

  for (int tile = 0; tile < NQ / TB; ++tile) {
    int c0 = tile * TB;
    // stage candidate tile
#pragma unroll
    for (int i = 0; i < 8; ++i) {
      int e = t + i * 512;             // 0..4095 (128 rows x 32 f4)
      int r = e >> 5, c4 = (e & 31) << 2;
      *(float4*)&cf[r][c4] = *(const float4*)&vb[(size_t)(c0 + r) * CD + c4];
    }
    if (t < TB) xc[t] = xb[c0 + t];
    __syncthreads();

    // 64x128 distance tile, 4q x 4c microtile, k vectorized by 4
    float acc[4][4];
#pragma unroll
    for (int i = 0; i < 4; ++i)
#pragma unroll
      for (int j = 0; j < 4; ++j) acc[i][j] = 0.f;

#pragma unroll
    for (int k = 0; k < CD; k += 4) {
      float4 a[4], cv[4];
#pragma unroll
      for (int i = 0; i < 4; ++i) a[i] = *(float4*)&qf[qt + 16 * i][k];
#pragma unroll
      for (int j = 0; j < 4; ++j) cv[j] = *(float4*)&cf[ct + 32 * j][k];
#pragma unroll
      for (int i = 0; i < 4; ++i)
#pragma unroll
        for (int j = 0; j < 4; ++j)
          acc[i][j] += a[i].x * cv[j].x + a[i].y * cv[j].y +
                       a[i].z * cv[j].z + a[i].w * cv[j].w;
    }
#pragma unroll
    for (int i = 0; i < 4; ++i) {
      int q = qt + 16 * i;
#pragma unroll
      for (int j = 0; j < 4; ++j) {
        int c = ct + 32 * j;
        sd[q][c] = xq[q] + xc[c] - 2.0f * acc[i][j];
      }
    }
    __syncthreads();

    // selection: wave w handles queries 8w..8w+7; 2 candidates per lane
#pragma unroll
    for (int u = 0; u < 8; ++u) {
      int q = 8 * w + u;
      float d0 = sd[q][lane];
      float d1 = sd[q][lane + 64];
      int ci0 = c0 + lane, ci1 = c0 + lane + 64;
      unsigned long long m0 = __ballot(d0 < tau[u] && ci0 != qg[u]);
      while (m0) {
        int l = __builtin_ctzll(m0); m0 &= m0 - 1;
        float d = __shfl(d0, l);
        insert1(ed[u], ei[u], tau[u], d, c0 + l);
      }
      unsigned long long m1 = __ballot(d1 < tau[u] && ci1 != qg[u]);
      while (m1) {
        int l = __builtin_ctzll(m1); m1 &= m1 - 1;
        float d = __shfl(d1, l);
        insert1(ed[u], ei[u], tau[u], d, c0 + 64 + l);
      }
    }
    __syncthreads();
  }

  // lanes 0..19 hold the sorted top-20 indices
  if (lane < KNN) {
#pragma unroll
    for (int u = 0; u < 8; ++u) {
      idxout[(size_t)(b * NQ + q0 + 8 * w + u) * KNN + lane] = ei[u];
    }
  }
}

// ---------------- gather 20 neighbor rows, elementwise max, write (B,C,N) ----------------
__global__ __launch_bounds__(256) void k_gather(const float* __restrict__ vf,
                                                const int* __restrict__ idx,
                                                float* __restrict__ out) {
  __shared__ float tile[CD][65];
  int blk = blockIdx.x;            // 256 blocks: 64 n's each
  int b = blk >> 7;
  int n0 = (blk & 127) * 64;
  int w = threadIdx.x >> 6, lane = threadIdx.x & 63;
  const float* vb = vf + (size_t)b * NQ * CD;
  for (int s = 0; s < 16; ++s) {
    int nl = w * 16 + s;
    const int* id = idx + (size_t)(b * NQ + n0 + nl) * KNN;
    float m0 = -3.0e38f, m1 = -3.0e38f;
#pragma unroll
    for (int j = 0; j < KNN; ++j) {
      const float* row = vb + (size_t)id[j] * CD;
      m0 = fmaxf(m0, row[lane]);
      m1 = fmaxf(m1, row[lane + 64]);
    }
    tile[lane][nl] = m0;
    tile[lane + 64][nl] = m1;
  }
  __syncthreads();
  float* ob = out + (size_t)b * CD * NQ;
  for (int i = 0; i < 32; ++i) {
    int e = threadIdx.x + i * 256;   // 0..8191 = 128 c x 64 n
    int c = e >> 6, j = e & 63;
    ob[(size_t)c * NQ + n0 + j] = tile[c][j];
  }
}

extern "C" void kernel_launch(void* const* d_in, const int* in_sizes, int n_in,
                              void* d_out, int out_size, void* d_ws, size_t ws_size,
                              hipStream_t stream) {
  const float* x = (const float*)d_in[0];  // vertex_feat (B,C,N)
  float* vf = (float*)d_ws;                                    // 8 MB
  float* xx = (float*)((char*)d_ws + (size_t)NB * NQ * CD * 4); // 64 KB
  int* idx = (int*)((char*)d_ws + (size_t)NB * NQ * CD * 4 + (size_t)NB * NQ * 4);
  float* out = (float*)d_out;

  k_transpose<<<dim3(NB * 256 * 4), dim3(256), 0, stream>>>(x, vf);
  k_xx<<<dim3(NB * NQ / 256), dim3(256), 0, stream>>>(vf, xx);
  k_knn<<<dim3(NB * NQ / QB), dim3(512), 0, stream>>>(vf, xx, idx);
  k_gather<<<dim3(NB * NQ / 64), dim3(256), 0, stream>>>(vf, idx, out);
}

// Round 3
// 550.814 us; speedup vs baseline: 1.4184x; 1.4184x over previous
//
#include <hip/hip_runtime.h>

#define NQ 8192
#define CD 128
#define NB 2
#define KNN 20
#define QB 64    // queries per block (knn kernel)
#define TB 128   // candidates per tile
#define LDC 136  // chi/clo row stride in f16 elems (+8 pad)
#define LDSD 132 // sd row stride in f32
#define LOSCALE 4096.0f
#define LOINV (1.0f / 4096.0f)

using f16x8 = __attribute__((ext_vector_type(8))) _Float16;
using f32x4 = __attribute__((ext_vector_type(4))) float;

// ---------------- transpose (B,C,N) f32 -> (B,N,C) split f16 hi + scaled lo ----------------
__global__ __launch_bounds__(256) void k_transpose(const float* __restrict__ x,
                                                   _Float16* __restrict__ vhi,
                                                   _Float16* __restrict__ vlo) {
  __shared__ float tile[32][33];
  int bid = blockIdx.x;
  int ctile = bid & 3;            // CD/32 = 4
  int ntile = (bid >> 2) & 255;   // NQ/32 = 256
  int b = bid >> 10;
  int c0 = ctile << 5, n0 = ntile << 5;
  int tx = threadIdx.x & 31, ty = threadIdx.x >> 5;  // ty 0..7
  const float* xb = x + (size_t)b * CD * NQ;
  _Float16* hb = vhi + (size_t)b * NQ * CD;
  _Float16* lb = vlo + (size_t)b * NQ * CD;
#pragma unroll
  for (int i = 0; i < 4; ++i) {
    int c = ty + (i << 3);
    tile[c][tx] = xb[(size_t)(c0 + c) * NQ + n0 + tx];
  }
  __syncthreads();
#pragma unroll
  for (int i = 0; i < 4; ++i) {
    int n = ty + (i << 3);
    float v = tile[tx][n];
    _Float16 h = (_Float16)v;
    float hf = (float)h;
    _Float16 l = (_Float16)((v - hf) * LOSCALE);  // exact pow2 scale, keeps lo normal
    size_t o = (size_t)(n0 + n) * CD + c0 + tx;
    hb[o] = h;
    lb[o] = l;
  }
}

// ---------------- per-row sum of squares (reads x in (B,C,N), coalesced) ----------------
__global__ __launch_bounds__(256) void k_xx(const float* __restrict__ x,
                                            float* __restrict__ xx) {
  int n = blockIdx.x * 256 + threadIdx.x;
  int b = blockIdx.y;
  const float* xb = x + (size_t)b * CD * NQ + n;
  float s = 0.f;
#pragma unroll
  for (int c = 0; c < CD; ++c) {
    float v = xb[(size_t)c * NQ];
    s += v * v;
  }
  xx[(size_t)b * NQ + n] = s;
}

// ---------------- fused split-f16 MFMA distance + exact top-20 ----------------
// 256 blocks (128 q-blocks/batch), 512 threads (8 waves).
// Wave w: MFMA strip = q rows [16*(w&3),+16) x cand cols [64*(w>>2),+64);
//          selection owns queries 8w..8w+7 over all 128 cols.
__global__ __launch_bounds__(512, 1) void k_knn(const _Float16* __restrict__ vhi,
                                                const _Float16* __restrict__ vlo,
                                                const float* __restrict__ xx,
                                                int* __restrict__ idxout) {
  __shared__ _Float16 chi[TB][LDC];
  __shared__ _Float16 clo[TB][LDC];
  __shared__ float sd[QB][LDSD];
  __shared__ float xq[QB];
  __shared__ float xc[TB];

  const int t = threadIdx.x;
  const int blk = blockIdx.x;
  const int b = blk >> 7;
  const int q0 = (blk & 127) * QB;
  const _Float16* hb = vhi + (size_t)b * NQ * CD;
  const _Float16* lb = vlo + (size_t)b * NQ * CD;
  const float* xb = xx + (size_t)b * NQ;

  const int lane = t & 63, w = t >> 6;
  const int strip = w & 3;   // q-row strip
  const int half = w >> 2;   // candidate col half

  if (t < QB) xq[t] = xb[q0 + t];

  // persistent A fragments: row = q0+16*strip+(lane&15), k = ks*32 + (lane>>4)*8
  f16x8 ahi[4], alo[4];
  {
    int row = q0 + 16 * strip + (lane & 15);
    int kof = (lane >> 4) * 8;
    const _Float16* hrow = hb + (size_t)row * CD + kof;
    const _Float16* lrow = lb + (size_t)row * CD + kof;
#pragma unroll
    for (int ks = 0; ks < 4; ++ks) {
      ahi[ks] = *(const f16x8*)(hrow + ks * 32);
      alo[ks] = *(const f16x8*)(lrow + ks * 32);
    }
  }

  // top-20 state: 8 queries per wave; sorted ascending, rank r lives in lane r
  float ed[8]; int ei[8]; float tau[8];
#pragma unroll
  for (int u = 0; u < 8; ++u) { ed[u] = 3.0e38f; ei[u] = 0; tau[u] = 3.0e38f; }

  auto insert1 = [&](float& edu, int& eiu, float& tauu, float d, int ci) {
    float cur = edu; int curi = eiu;
    float sh = __shfl_up(cur, 1);
    int shi = __shfl_up(curi, 1);
    bool cprev = (lane > 0) && (d < sh);
    bool ccur = d < cur;
    edu = ccur ? (cprev ? sh : d) : cur;
    eiu = ccur ? (cprev ? shi : ci) : curi;
    tauu = __shfl(edu, 19);
  };

  for (int tile = 0; tile < NQ / TB; ++tile) {
    const int c0 = tile * TB;
    __syncthreads();  // prev selection done with sd; prev MFMA done with chi/clo

    // stage candidate tile hi/lo: 2048 chunks of 8 f16 per array
#pragma unroll
    for (int i = 0; i < 4; ++i) {
      int e = t + i * 512;
      int r = e >> 4, ch = (e & 15) * 8;
      *(f16x8*)&chi[r][ch] = *(const f16x8*)(hb + (size_t)(c0 + r) * CD + ch);
      *(f16x8*)&clo[r][ch] = *(const f16x8*)(lb + (size_t)(c0 + r) * CD + ch);
    }
    if (t < TB) xc[t] = xb[c0 + t];
    __syncthreads();

    // MFMA: 4 fragments (16q x 64c), passes hh -> accA, (h*lo' + lo*h') -> accB
    f32x4 accA[4], accB[4];
#pragma unroll
    for (int f = 0; f < 4; ++f) {
      accA[f] = (f32x4){0.f, 0.f, 0.f, 0.f};
      accB[f] = (f32x4){0.f, 0.f, 0.f, 0.f};
    }
    const int kof = (lane >> 4) * 8;
#pragma unroll
    for (int ks = 0; ks < 4; ++ks) {
#pragma unroll
      for (int f = 0; f < 4; ++f) {
        int c = 64 * half + 16 * f + (lane & 15);
        f16x8 bhi = *(const f16x8*)&chi[c][ks * 32 + kof];
        f16x8 blo = *(const f16x8*)&clo[c][ks * 32 + kof];
        accA[f] = __builtin_amdgcn_mfma_f32_16x16x32_f16(ahi[ks], bhi, accA[f], 0, 0, 0);
        accB[f] = __builtin_amdgcn_mfma_f32_16x16x32_f16(ahi[ks], blo, accB[f], 0, 0, 0);
        accB[f] = __builtin_amdgcn_mfma_f32_16x16x32_f16(alo[ks], bhi, accB[f], 0, 0, 0);
      }
    }

    // distances to LDS; match reference association: (xx_q + (-2*dot)) + xx_c
#pragma unroll
    for (int f = 0; f < 4; ++f) {
      int c = 64 * half + 16 * f + (lane & 15);
      float xcv = xc[c];
#pragma unroll
      for (int r = 0; r < 4; ++r) {
        int qrow = 16 * strip + (lane >> 4) * 4 + r;
        float dot = accA[f][r] + accB[f][r] * LOINV;
        float tmp = xq[qrow] + (-2.0f * dot);
        sd[qrow][c] = tmp + xcv;
      }
    }
    __syncthreads();

    // selection: wave w owns queries 8w..8w+7 over all 128 cols
#pragma unroll
    for (int u = 0; u < 8; ++u) {
      int q = 8 * w + u;
      int qg = q0 + q;
      float d0 = sd[q][lane];
      float d1 = sd[q][64 + lane];
      unsigned long long m0 = __ballot(d0 < tau[u] && (c0 + lane) != qg);
      while (m0) {
        int l = __builtin_ctzll(m0); m0 &= m0 - 1;
        float d = __shfl(d0, l);
        if (d < tau[u]) insert1(ed[u], ei[u], tau[u], d, c0 + l);
      }
      unsigned long long m1 = __ballot(d1 < tau[u] && (c0 + 64 + lane) != qg);
      while (m1) {
        int l = __builtin_ctzll(m1); m1 &= m1 - 1;
        float d = __shfl(d1, l);
        if (d < tau[u]) insert1(ed[u], ei[u], tau[u], d, c0 + 64 + l);
      }
    }
  }

  if (lane < KNN) {
#pragma unroll
    for (int u = 0; u < 8; ++u)
      idxout[(size_t)(b * NQ + q0 + 8 * w + u) * KNN + lane] = ei[u];
  }
}

// ---------------- gather 20 neighbors (hi + lo/4096), max, write (B,C,N) ----------------
__global__ __launch_bounds__(256) void k_gather(const _Float16* __restrict__ vhi,
                                                const _Float16* __restrict__ vlo,
                                                const int* __restrict__ idx,
                                                float* __restrict__ out) {
  __shared__ float tile[CD][65];
  int blk = blockIdx.x;            // 256 blocks: 64 n's each
  int b = blk >> 7;
  int n0 = (blk & 127) * 64;
  int w = threadIdx.x >> 6, lane = threadIdx.x & 63;
  const _Float16* hb = vhi + (size_t)b * NQ * CD;
  const _Float16* lb = vlo + (size_t)b * NQ * CD;
  for (int s = 0; s < 16; ++s) {
    int nl = w * 16 + s;
    const int* id = idx + (size_t)(b * NQ + n0 + nl) * KNN;
    float m0 = -3.0e38f, m1 = -3.0e38f;
#pragma unroll
    for (int j = 0; j < KNN; ++j) {
      size_t ro = (size_t)id[j] * CD;
      float v0 = fmaf((float)lb[ro + lane], LOINV, (float)hb[ro + lane]);
      float v1 = fmaf((float)lb[ro + 64 + lane], LOINV, (float)hb[ro + 64 + lane]);
      m0 = fmaxf(m0, v0);
      m1 = fmaxf(m1, v1);
    }
    tile[lane][nl] = m0;
    tile[lane + 64][nl] = m1;
  }
  __syncthreads();
  float* ob = out + (size_t)b * CD * NQ;
  for (int i = 0; i < 32; ++i) {
    int e = threadIdx.x + i * 256;   // 128 c x 64 n
    int c = e >> 6, j = e & 63;
    ob[(size_t)c * NQ + n0 + j] = tile[c][j];
  }
}

extern "C" void kernel_launch(void* const* d_in, const int* in_sizes, int n_in,
                              void* d_out, int out_size, void* d_ws, size_t ws_size,
                              hipStream_t stream) {
  const float* x = (const float*)d_in[0];  // vertex_feat (B,C,N)
  size_t velems = (size_t)NB * NQ * CD;
  _Float16* vhi = (_Float16*)d_ws;                           // 4 MB
  _Float16* vlo = vhi + velems;                              // 4 MB
  float* xx = (float*)((char*)d_ws + velems * 4);            // 64 KB
  int* idx = (int*)((char*)xx + (size_t)NB * NQ * 4);        // 1.3 MB
  float* out = (float*)d_out;

  k_transpose<<<dim3(NB * 256 * 4), dim3(256), 0, stream>>>(x, vhi, vlo);
  k_xx<<<dim3(NQ / 256, NB), dim3(256), 0, stream>>>(x, xx);
  k_knn<<<dim3(NB * NQ / QB), dim3(512), 0, stream>>>(vhi, vlo, xx, idx);
  k_gather<<<dim3(NB * NQ / 64), dim3(256), 0, stream>>>(vhi, vlo, idx, out);
}

// Round 4
// 370.567 us; speedup vs baseline: 2.1083x; 1.4864x over previous
//
#include <hip/hip_runtime.h>

#define NQ 8192
#define CD 128
#define NB 2
#define KNN 20
#define QB 32    // queries per block (knn kernel) -> 512 blocks = 2/CU
#define TB 128   // candidates per tile
#define LDC 136  // chi/clo row stride in f16 elems (+8 pad)
#define LDSD 132 // sd row stride in f32
#define LOSCALE 4096.0f
#define LOINV (1.0f / 4096.0f)

using f16x8 = __attribute__((ext_vector_type(8))) _Float16;
using f16x2 = __attribute__((ext_vector_type(2))) _Float16;
using f32x4 = __attribute__((ext_vector_type(4))) float;

// ---------------- transpose (B,C,N) f32 -> (B,N,C) split f16 hi + scaled lo ----------------
__global__ __launch_bounds__(256) void k_transpose(const float* __restrict__ x,
                                                   _Float16* __restrict__ vhi,
                                                   _Float16* __restrict__ vlo) {
  __shared__ float tile[32][33];
  int bid = blockIdx.x;
  int ctile = bid & 3;            // CD/32 = 4
  int ntile = (bid >> 2) & 255;   // NQ/32 = 256
  int b = bid >> 10;
  int c0 = ctile << 5, n0 = ntile << 5;
  int tx = threadIdx.x & 31, ty = threadIdx.x >> 5;  // ty 0..7
  const float* xb = x + (size_t)b * CD * NQ;
  _Float16* hb = vhi + (size_t)b * NQ * CD;
  _Float16* lb = vlo + (size_t)b * NQ * CD;
#pragma unroll
  for (int i = 0; i < 4; ++i) {
    int c = ty + (i << 3);
    tile[c][tx] = xb[(size_t)(c0 + c) * NQ + n0 + tx];
  }
  __syncthreads();
#pragma unroll
  for (int i = 0; i < 4; ++i) {
    int n = ty + (i << 3);
    float v = tile[tx][n];
    _Float16 h = (_Float16)v;
    float hf = (float)h;
    _Float16 l = (_Float16)((v - hf) * LOSCALE);  // exact pow2 scale keeps lo normal
    size_t o = (size_t)(n0 + n) * CD + c0 + tx;
    hb[o] = h;
    lb[o] = l;
  }
}

// ---------------- per-row sum of squares (reads x in (B,C,N), coalesced) ----------------
__global__ __launch_bounds__(256) void k_xx(const float* __restrict__ x,
                                            float* __restrict__ xx) {
  int n = blockIdx.x * 256 + threadIdx.x;
  int b = blockIdx.y;
  const float* xb = x + (size_t)b * CD * NQ + n;
  float s = 0.f;
#pragma unroll
  for (int c = 0; c < CD; ++c) {
    float v = xb[(size_t)c * NQ];
    s += v * v;
  }
  xx[(size_t)b * NQ + n] = s;
}

// ---------------- fused split-f16 MFMA distance + exact top-20 ----------------
// 512 blocks (256 q-blocks/batch), 512 threads (8 waves), 2 blocks/CU.
// Wave w: MFMA strip = q rows [16*(w&1),+16) x cand cols [32*(w>>1),+32);
//          selection owns queries 4w..4w+3 over all 128 cols.
// LDS: ubuf = chi[128][136] f16 (34.8 KB, aliased by sd[32][132] f32 16.9 KB)
//      + clo[128][136] (34.8 KB) + xq/xc -> ~70.3 KB -> 2 blocks/CU.
__global__ __launch_bounds__(512, 4) void k_knn(const _Float16* __restrict__ vhi,
                                                const _Float16* __restrict__ vlo,
                                                const float* __restrict__ xx,
                                                int* __restrict__ idxout) {
  __shared__ char ubuf[TB * LDC * 2];
  __shared__ _Float16 clo[TB][LDC];
  __shared__ float xq[QB];
  __shared__ float xc[TB];
  auto chi = (_Float16(*)[LDC])ubuf;
  auto sd = (float(*)[LDSD])ubuf;

  const int t = threadIdx.x;
  const int blk = blockIdx.x;
  const int b = blk >> 8;
  const int q0 = (blk & 255) * QB;
  const _Float16* hb = vhi + (size_t)b * NQ * CD;
  const _Float16* lb = vlo + (size_t)b * NQ * CD;
  const float* xb = xx + (size_t)b * NQ;

  const int lane = t & 63, w = t >> 6;
  const int strip = w & 1;    // q-row strip (16 rows)
  const int quarter = w >> 1; // candidate col quarter (32 cols)

  if (t < QB) xq[t] = xb[q0 + t];

  // persistent A fragments: row = q0+16*strip+(lane&15), k = ks*32 + (lane>>4)*8
  f16x8 ahi[4], alo[4];
  {
    int row = q0 + 16 * strip + (lane & 15);
    int kof = (lane >> 4) * 8;
    const _Float16* hrow = hb + (size_t)row * CD + kof;
    const _Float16* lrow = lb + (size_t)row * CD + kof;
#pragma unroll
    for (int ks = 0; ks < 4; ++ks) {
      ahi[ks] = *(const f16x8*)(hrow + ks * 32);
      alo[ks] = *(const f16x8*)(lrow + ks * 32);
    }
  }

  // top-20 state: 4 queries per wave; sorted ascending, rank r lives in lane r
  float ed[4]; int ei[4]; float tau[4];
#pragma unroll
  for (int u = 0; u < 4; ++u) { ed[u] = 3.0e38f; ei[u] = 0; tau[u] = 3.0e38f; }

  // insert WITHOUT tau update (tau maintained stale-per-walk by caller)
  auto insert1 = [&](float& edu, int& eiu, float d, int ci) {
    float sh = __shfl_up(edu, 1);
    int shi = __shfl_up(eiu, 1);
    bool cprev = (lane > 0) && (d < sh);
    bool ccur = d < edu;
    edu = ccur ? (cprev ? sh : d) : edu;
    eiu = ccur ? (cprev ? shi : ci) : eiu;
  };

  for (int tile = 0; tile < NQ / TB; ++tile) {
    const int c0 = tile * TB;
    __syncthreads();  // B1: prev selection done with sd(=chi region), prev MFMA done

    // stage candidate tile hi/lo: 2048 chunks of 8 f16 per array
#pragma unroll
    for (int i = 0; i < 4; ++i) {
      int e = t + i * 512;
      int r = e >> 4, ch = (e & 15) * 8;
      *(f16x8*)&chi[r][ch] = *(const f16x8*)(hb + (size_t)(c0 + r) * CD + ch);
      *(f16x8*)&clo[r][ch] = *(const f16x8*)(lb + (size_t)(c0 + r) * CD + ch);
    }
    if (t < TB) xc[t] = xb[c0 + t];
    __syncthreads();  // B2: staged

    // MFMA: 2 fragments (16q x 32c), passes hh -> accA, (h*lo' + lo*h') -> accB
    f32x4 accA[2], accB[2];
#pragma unroll
    for (int f = 0; f < 2; ++f) {
      accA[f] = (f32x4){0.f, 0.f, 0.f, 0.f};
      accB[f] = (f32x4){0.f, 0.f, 0.f, 0.f};
    }
    const int kof = (lane >> 4) * 8;
#pragma unroll
    for (int ks = 0; ks < 4; ++ks) {
#pragma unroll
      for (int f = 0; f < 2; ++f) {
        int c = 32 * quarter + 16 * f + (lane & 15);
        f16x8 bhi = *(const f16x8*)&chi[c][ks * 32 + kof];
        f16x8 blo = *(const f16x8*)&clo[c][ks * 32 + kof];
        accA[f] = __builtin_amdgcn_mfma_f32_16x16x32_f16(ahi[ks], bhi, accA[f], 0, 0, 0);
        accB[f] = __builtin_amdgcn_mfma_f32_16x16x32_f16(ahi[ks], blo, accB[f], 0, 0, 0);
        accB[f] = __builtin_amdgcn_mfma_f32_16x16x32_f16(alo[ks], bhi, accB[f], 0, 0, 0);
      }
    }

    // distances to registers (reference association), then LDS after barrier
    float dv[2][4];
#pragma unroll
    for (int f = 0; f < 2; ++f) {
      int c = 32 * quarter + 16 * f + (lane & 15);
      float xcv = xc[c];
#pragma unroll
      for (int r = 0; r < 4; ++r) {
        int qrow = 16 * strip + (lane >> 4) * 4 + r;
        float dot = accA[f][r] + accB[f][r] * LOINV;
        float tmp = xq[qrow] + (-2.0f * dot);
        dv[f][r] = tmp + xcv;
      }
    }
    __syncthreads();  // B3: all waves done reading chi -> safe to overwrite with sd
#pragma unroll
    for (int f = 0; f < 2; ++f) {
      int c = 32 * quarter + 16 * f + (lane & 15);
#pragma unroll
      for (int r = 0; r < 4; ++r) {
        int qrow = 16 * strip + (lane >> 4) * 4 + r;
        sd[qrow][c] = dv[f][r];
      }
    }
    __syncthreads();  // B4: sd ready

    // selection: wave w owns queries 4w..4w+3 over all 128 cols
#pragma unroll
    for (int u = 0; u < 4; ++u) {
      int q = 4 * w + u;
      int qg = q0 + q;
      float d0 = sd[q][lane];
      float d1 = sd[q][64 + lane];
      int cnt = 0;
      unsigned long long m0 = __ballot(d0 < tau[u] && (c0 + lane) != qg);
      while (m0) {
        int l = __builtin_ctzll(m0); m0 &= m0 - 1;
        float d = __shfl(d0, l);
        if (d < tau[u]) {
          insert1(ed[u], ei[u], d, c0 + l);
          if ((++cnt & 7) == 0) tau[u] = __shfl(ed[u], 19);
        }
      }
      tau[u] = __shfl(ed[u], 19);
      unsigned long long m1 = __ballot(d1 < tau[u] && (c0 + 64 + lane) != qg);
      while (m1) {
        int l = __builtin_ctzll(m1); m1 &= m1 - 1;
        float d = __shfl(d1, l);
        if (d < tau[u]) {
          insert1(ed[u], ei[u], d, c0 + 64 + l);
          if ((++cnt & 7) == 0) tau[u] = __shfl(ed[u], 19);
        }
      }
      tau[u] = __shfl(ed[u], 19);
    }
  }

  if (lane < KNN) {
#pragma unroll
    for (int u = 0; u < 4; ++u)
      idxout[(size_t)(b * NQ + q0 + 4 * w + u) * KNN + lane] = ei[u];
  }
}

// ---------------- gather 20 neighbors (hi + lo/4096), max, write (B,C,N) ----------------
__global__ __launch_bounds__(256) void k_gather(const _Float16* __restrict__ vhi,
                                                const _Float16* __restrict__ vlo,
                                                const int* __restrict__ idx,
                                                float* __restrict__ out) {
  __shared__ float tile[CD][65];
  int blk = blockIdx.x;            // 256 blocks: 64 n's each
  int b = blk >> 7;
  int n0 = (blk & 127) * 64;
  int w = threadIdx.x >> 6, lane = threadIdx.x & 63;
  const _Float16* hb = vhi + (size_t)b * NQ * CD;
  const _Float16* lb = vlo + (size_t)b * NQ * CD;
  for (int s = 0; s < 16; ++s) {
    int nl = w * 16 + s;
    const int* id = idx + (size_t)(b * NQ + n0 + nl) * KNN;
    float ma = -3.0e38f, mb = -3.0e38f;  // cols 2*lane, 2*lane+1
#pragma unroll
    for (int j = 0; j < KNN; ++j) {
      size_t ro = (size_t)id[j] * CD + 2 * lane;
      f16x2 h = *(const f16x2*)(hb + ro);
      f16x2 l = *(const f16x2*)(lb + ro);
      ma = fmaxf(ma, fmaf((float)l[0], LOINV, (float)h[0]));
      mb = fmaxf(mb, fmaf((float)l[1], LOINV, (float)h[1]));
    }
    tile[2 * lane][nl] = ma;
    tile[2 * lane + 1][nl] = mb;
  }
  __syncthreads();
  float* ob = out + (size_t)b * CD * NQ;
  for (int i = 0; i < 32; ++i) {
    int e = threadIdx.x + i * 256;   // 128 c x 64 n
    int c = e >> 6, j = e & 63;
    ob[(size_t)c * NQ + n0 + j] = tile[c][j];
  }
}

extern "C" void kernel_launch(void* const* d_in, const int* in_sizes, int n_in,
                              void* d_out, int out_size, void* d_ws, size_t ws_size,
                              hipStream_t stream) {
  const float* x = (const float*)d_in[0];  // vertex_feat (B,C,N)
  size_t velems = (size_t)NB * NQ * CD;
  _Float16* vhi = (_Float16*)d_ws;                           // 4 MB
  _Float16* vlo = vhi + velems;                              // 4 MB
  float* xx = (float*)((char*)d_ws + velems * 4);            // 64 KB
  int* idx = (int*)((char*)xx + (size_t)NB * NQ * 4);        // 1.3 MB
  float* out = (float*)d_out;

  k_transpose<<<dim3(NB * 256 * 4), dim3(256), 0, stream>>>(x, vhi, vlo);
  k_xx<<<dim3(NQ / 256, NB), dim3(256), 0, stream>>>(x, xx);
  k_knn<<<dim3(NB * NQ / QB), dim3(512), 0, stream>>>(vhi, vlo, xx, idx);
  k_gather<<<dim3(NB * NQ / 64), dim3(256), 0, stream>>>(vhi, vlo, idx, out);
}